// Round 9
// baseline (249.854 us; speedup 1.0000x reference)
//
#include <hip/hip_runtime.h>
#include <hip/hip_bf16.h>

// Problem constants
#define NB   128     // frames
#define NP   4096    // points per frame
#define C3   512

typedef __bf16 bf16x8 __attribute__((ext_vector_type(8)));
typedef __bf16 bf16x4 __attribute__((ext_vector_type(4)));
typedef float  f32x4  __attribute__((ext_vector_type(4)));

// ws layout
#define WS_PART 0         // [128][512] f32 per-frame global-branch partial maxes
#define WS_CNT  262144    // [16] int group-arrival counters (memset each launch)

// Grid (128 frames, 2 branches) = 256 blocks = 1/CU. 8 waves, __launch_bounds__(512,2)
// (total-reg cap 256; shared afr[] register file keeps demand ~215).
// WAVE SPECIALIZATION: waves 0-3 = producers (L1 own-16pt + L2 32ch-slice),
// waves 4-7 = consumers (P2: 128-ch W3 slice resident in 128 VGPRs, 128
// MFMA/macro streamed barrier-to-barrier). Each SIMD hosts 1 producer + 1
// consumer -> MFMA pipe stays fed through producer phases (m114 overlap).
// 64 macros of 64 pts; h1f/h2f double-buffered, 2 barriers/macro.
// Weights fragment-gathered from global (L2-cached) - no prep kernel.
// Global branch: per-frame partial + last-arriver-per-group reduction
// (device fences + atomic counter) - no gather kernel.
__global__ __launch_bounds__(512, 2) void main_kernel(
    const float* __restrict__ pc, const float* __restrict__ tt, const int* __restrict__ idx,
    const float* __restrict__ Wg1, const float* __restrict__ bg1,
    const float* __restrict__ Wg2, const float* __restrict__ bg2,
    const float* __restrict__ Wg3, const float* __restrict__ bg3,
    const float* __restrict__ Wl1, const float* __restrict__ bl1,
    const float* __restrict__ Wl2, const float* __restrict__ bl2,
    const float* __restrict__ Wl3, const float* __restrict__ bl3,
    float* __restrict__ out, char* __restrict__ ws) {
    __shared__ __align__(16) char smem[49928];
    __bf16* h2f = (__bf16*)smem;               // 2 x 8192 elems (32768 B)
    __bf16* h1f = (__bf16*)(smem + 32768);     // 2 x 4096 elems (16384 B)
    float*  b1s = (float*)(smem + 49152);      // 64 f32
    float*  b2s = (float*)(smem + 49408);      // 128 f32
    int*  sflag = (int*)(smem + 49920);

    const int tid = threadIdx.x, lane = tid & 63, wave = tid >> 6;
    const int quad = lane >> 4, l15 = lane & 15;
    const int branch = blockIdx.y, frame = blockIdx.x;
    const bool prod = (wave < 4);

    const float* pcx = pc + (size_t)frame * 3 * NP;

    // pc passthrough: branch-0 block copies its frame (overlaps everything)
    if (branch == 0) {
        const f32x4* ps = (const f32x4*)pcx;
        f32x4* pd = (f32x4*)(out + NB * 2 * C3 + (size_t)frame * 3 * NP);
        #pragma unroll
        for (int j = 0; j < 6; ++j) pd[j * 512 + tid] = ps[j * 512 + tid];
    }

    const float* W1 = branch ? Wl1 : Wg1;
    const float* W2 = branch ? Wl2 : Wg2;
    const float* W3 = branch ? Wl3 : Wg3;
    const float* b1 = branch ? bl1 : bg1;
    const float* b2 = branch ? bl2 : bg2;
    const float* b3 = branch ? bl3 : bg3;

    if (tid < 64)  b1s[tid] = b1[tid];
    if (tid < 128) b2s[tid] = b2[tid];

    // Shared A-fragment register file (role-dependent contents, one live range):
    //  producers: afr[0][mi] = W1 frags (K32, k>=4 zero); afr[1][mi*2+ks] = W2 slice
    //  consumers: afr[mi][ks] = W3 slice 128ch x K128 (128 VGPRs)
    bf16x8 afr[8][4];
    if (prod) {
        #pragma unroll
        for (int mi = 0; mi < 4; ++mi) {
            bf16x8 f;
            #pragma unroll
            for (int j = 0; j < 8; ++j)
                f[j] = (quad == 0 && j < 4) ? (__bf16)W1[j * 64 + mi * 16 + l15] : (__bf16)0.0f;
            afr[0][mi] = f;
        }
        #pragma unroll
        for (int mi = 0; mi < 2; ++mi)
            #pragma unroll
            for (int ks = 0; ks < 2; ++ks) {
                bf16x8 f;
                #pragma unroll
                for (int j = 0; j < 8; ++j)
                    f[j] = (__bf16)W2[(ks * 32 + quad * 8 + j) * 128 + wave * 32 + mi * 16 + l15];
                afr[1][mi * 2 + ks] = f;
            }
    } else {
        const int cb = (wave - 4) * 128;
        #pragma unroll
        for (int mi = 0; mi < 8; ++mi)
            #pragma unroll
            for (int ks = 0; ks < 4; ++ks) {
                bf16x8 f;
                #pragma unroll
                for (int j = 0; j < 8; ++j)
                    f[j] = (__bf16)W3[(ks * 32 + quad * 8 + j) * 512 + cb + mi * 16 + l15];
                afr[mi][ks] = f;
            }
    }

    const float tval = tt[frame];
    const f32x4 zf = {0.0f, 0.0f, 0.0f, 0.0f};
    f32x4 runmax[8];
    #pragma unroll
    for (int mi = 0; mi < 8; ++mi) runmax[mi] = (f32x4){-1e30f, -1e30f, -1e30f, -1e30f};

    const int pw = wave * 16 + l15;   // producer's own 16 pts within a macro

    // L1: own 16 pts of macro m -> dst h1f buffer (fragment-chunk order)
    auto do_l1 = [&](int m, __bf16* dst) {
        const int p = m * 64 + pw;
        const float xx = pcx[p], xy = pcx[NP + p], xz = pcx[2 * NP + p];
        bf16x8 xb;
        #pragma unroll
        for (int j = 0; j < 8; ++j) xb[j] = (__bf16)0.0f;
        if (quad == 0) { xb[0] = (__bf16)xx; xb[1] = (__bf16)xy; xb[2] = (__bf16)xz; xb[3] = (__bf16)tval; }
        #pragma unroll
        for (int mi = 0; mi < 4; ++mi) {
            f32x4 c = __builtin_amdgcn_mfma_f32_16x16x32_bf16(afr[0][mi], xb, zf, 0, 0, 0);
            f32x4 bv = *(const f32x4*)(b1s + mi * 16 + quad * 4);
            bf16x4 pk;
            #pragma unroll
            for (int r = 0; r < 4; ++r) pk[r] = (__bf16)fmaxf(c[r] + bv[r], 0.0f);
            const int kq = (mi & 1) * 2 + (quad >> 1);
            *(bf16x4*)(dst + (wave * 2 + (mi >> 1)) * 512 + kq * 128 + l15 * 8 + (quad & 1) * 4) = pk;
        }
    };
    // L2: 32ch-slice (ch base wave*32) x 64 pts, K=64 -> dst h2f buffer
    auto do_l2 = [&](const __bf16* src, __bf16* dst) {
        #pragma unroll
        for (int ni = 0; ni < 4; ++ni) {
            bf16x8 q0 = *(const bf16x8*)(src + (ni * 2 + 0) * 512 + lane * 8);
            bf16x8 q1 = *(const bf16x8*)(src + (ni * 2 + 1) * 512 + lane * 8);
            #pragma unroll
            for (int mi = 0; mi < 2; ++mi) {
                f32x4 c = __builtin_amdgcn_mfma_f32_16x16x32_bf16(afr[1][mi * 2 + 0], q0, zf, 0, 0, 0);
                c = __builtin_amdgcn_mfma_f32_16x16x32_bf16(afr[1][mi * 2 + 1], q1, c, 0, 0, 0);
                f32x4 bv = *(const f32x4*)(b2s + wave * 32 + mi * 16 + quad * 4);
                bf16x4 pk;
                #pragma unroll
                for (int r = 0; r < 4; ++r) pk[r] = (__bf16)fmaxf(c[r] + bv[r], 0.0f);
                *(bf16x4*)(dst + (ni * 4 + wave) * 512 + (mi * 2 + (quad >> 1)) * 128 + l15 * 8 + (quad & 1) * 4) = pk;
            }
        }
    };
    // P2: one 16-pt group, 32 MFMA (128ch x K128), conflict-free reads
    auto p2_group = [&](const __bf16* hb, int ni) {
        bf16x8 bh[4];
        #pragma unroll
        for (int ks = 0; ks < 4; ++ks)
            bh[ks] = *(const bf16x8*)(hb + (ni * 4 + ks) * 512 + lane * 8);
        #pragma unroll
        for (int half = 0; half < 2; ++half) {
            f32x4 acc[4];
            #pragma unroll
            for (int ks = 0; ks < 4; ++ks)
                #pragma unroll
                for (int m2 = 0; m2 < 4; ++m2)
                    acc[m2] = __builtin_amdgcn_mfma_f32_16x16x32_bf16(
                        afr[half * 4 + m2][ks], bh[ks], ks ? acc[m2] : zf, 0, 0, 0);
            #pragma unroll
            for (int m2 = 0; m2 < 4; ++m2)
                #pragma unroll
                for (int r = 0; r < 4; ++r)
                    runmax[half * 4 + m2][r] = fmaxf(runmax[half * 4 + m2][r], acc[m2][r]);
        }
    };

    __syncthreads();                               // biases staged
    // prologue: L1(0)->h1f[0]; then L2(0)->h2f[0], L1(1)->h1f[1]
    if (prod) do_l1(0, h1f);
    __syncthreads();
    if (prod) { do_l2(h1f, h2f); do_l1(1, h1f + 4096); }
    __syncthreads();

    for (int m = 0; m < 64; ++m) {
        const __bf16* hb = h2f + (m & 1) * 8192;
        __bf16* hbn = h2f + ((m + 1) & 1) * 8192;
        // interval 1: consumers eat h2f[m]; producers build h2f[m+1] from h1f[m+1]
        if (!prod) { p2_group(hb, 0); p2_group(hb, 1); }
        else if (m < 63) do_l2(h1f + ((m + 1) & 1) * 4096, hbn);
        __syncthreads();
        // interval 2: consumers continue; producers build h1f[m+2]
        if (!prod) { p2_group(hb, 2); p2_group(hb, 3); }
        else if (m < 62) do_l1(m + 2, h1f + (m & 1) * 4096);
        __syncthreads();
    }

    // ---- finalize (consumers own all 512 ch): fold pts, bias3+relu, emit
    float* partial = (float*)(ws + WS_PART);
    if (!prod) {
        const int cb = (wave - 4) * 128;
        #pragma unroll
        for (int mi = 0; mi < 8; ++mi) {
            f32x4 v = runmax[mi];
            #pragma unroll
            for (int d = 1; d < 16; d <<= 1) {
                #pragma unroll
                for (int r = 0; r < 4; ++r) v[r] = fmaxf(v[r], __shfl_xor(v[r], d));
            }
            if (l15 == 0) {
                #pragma unroll
                for (int r = 0; r < 4; ++r) {
                    const int ch = cb + mi * 16 + quad * 4 + r;
                    const float fv = fmaxf(v[r] + b3[ch], 0.0f);
                    if (branch) out[(size_t)frame * (2 * C3) + C3 + ch] = fv;   // local: direct
                    else        partial[frame * C3 + ch] = fv;                  // global: partial
                }
            }
        }
    }

    // ---- global branch: last-arriver-per-group reduces & broadcasts
    if (branch == 0) {
        const int g = idx[frame];
        __threadfence();          // publish this block's partial[] (release)
        __syncthreads();
        if (tid == 0) {
            int gs = 0;
            for (int f2 = 0; f2 < NB; ++f2) gs += (idx[f2] == g);
            int old = atomicAdd((int*)(ws + WS_CNT) + g, 1);   // device-scope
            *sflag = (old == gs - 1);
        }
        __syncthreads();
        if (*sflag) {
            __threadfence();      // acquire: invalidate before reading peers' partials
            float mx = 0.0f;      // relu outputs >= 0
            for (int f2 = 0; f2 < NB; ++f2)
                if (idx[f2] == g) mx = fmaxf(mx, partial[f2 * C3 + tid]);
            for (int f2 = 0; f2 < NB; ++f2)
                if (idx[f2] == g) out[(size_t)f2 * (2 * C3) + tid] = mx;
        }
    }
}

extern "C" void kernel_launch(void* const* d_in, const int* in_sizes, int n_in,
                              void* d_out, int out_size, void* d_ws, size_t ws_size,
                              hipStream_t stream) {
    const float* pc  = (const float*)d_in[0];
    const float* tt  = (const float*)d_in[1];
    const int*   idx = (const int*)d_in[2];
    const float* Wg1 = (const float*)d_in[3];  const float* bg1 = (const float*)d_in[4];
    const float* Wg2 = (const float*)d_in[5];  const float* bg2 = (const float*)d_in[6];
    const float* Wg3 = (const float*)d_in[7];  const float* bg3 = (const float*)d_in[8];
    const float* Wl1 = (const float*)d_in[9];  const float* bl1 = (const float*)d_in[10];
    const float* Wl2 = (const float*)d_in[11]; const float* bl2 = (const float*)d_in[12];
    const float* Wl3 = (const float*)d_in[13]; const float* bl3 = (const float*)d_in[14];
    float* out = (float*)d_out;
    char*  ws  = (char*)d_ws;

    // zero the 16 group-arrival counters (ws is re-poisoned before every launch)
    hipMemsetAsync(ws + WS_CNT, 0, 16 * sizeof(int), stream);
    // single fused kernel: 128 frames x 2 branches = 256 blocks = 1 per CU
    main_kernel<<<dim3(128, 2), 512, 0, stream>>>(
        pc, tt, idx, Wg1, bg1, Wg2, bg2, Wg3, bg3,
        Wl1, bl1, Wl2, bl2, Wl3, bl3, out, ws);
}